// Round 5
// baseline (313.106 us; speedup 1.0000x reference)
//
#include <hip/hip_runtime.h>

// Problem constants (match reference)
#define B_   256
#define M_   16
#define A_   4096
#define NS_  1024
#define T_   64
#define AT_  (A_ + T_)

static constexpr float DTc = 0.001f;
static constexpr float DAc = 0.001f;
static constexpr float LOG_DT = -6.907755278982137f;   // ln(0.001)

// Output layout (flat, concatenated in reference return order)
static constexpr size_t OFF_AT    = 0;                         // A_t   (B*M)
static constexpr size_t OFF_Z     = 4096;                      // Z     (B*M)
static constexpr size_t OFF_ZNLL  = 8192;                      // Z_nll (B*M)
static constexpr size_t OFF_LNPY  = 12288;                     // lnPy  (B*M*NS)
static constexpr size_t OFF_LNP1Y = 12288 + 4194304;           // lnP1_y
static constexpr size_t OFF_VT    = 12288 + 2ull * 4194304;    // V_t_new (B*M*A)
static constexpr size_t OFF_SNV   = OFF_VT + 16777216ull;      // snv_new
static constexpr size_t OFF_ISYN  = OFF_SNV + 4194304ull;      // I_syn (B*M)

typedef float v4f __attribute__((ext_vector_type(4)));

static __device__ __forceinline__ v4f ldv(const float* p) {
    return *reinterpret_cast<const v4f*>(p);
}

// One row per WAVE. 64 lanes * 16 chunks * float4 = 4096 A-elements.
// Loop-carried distance-2 prefetch; intra-wave shuffle reduction; no LDS/barriers.
template<bool ZAL>
static __device__ __forceinline__ void do_row(
    const int row, const int lane, const int clk, const float inT,
    const float a_m, const float rp_m, const float ft_m, const float ztn,
    const float* __restrict__ V_t_old,
    const float* __restrict__ logS_t_old,
    const float* __restrict__ snv_in,
    const float* __restrict__ snlf,
    const float* __restrict__ Z_hist,
    float* __restrict__ out)
{
    const size_t rowA = (size_t)row * A_;
    const size_t rowS = (size_t)row * NS_;
    const size_t rowZ = (size_t)row * AT_;

    const float* pV  = V_t_old    + rowA + lane * 4;
    const float* pS  = logS_t_old + rowA + lane * 4;
    const float* pZb = Z_hist + rowZ + (clk + A_ - 4 - lane * 4);  // reversed window
    float*       pO  = out + OFF_VT + rowA + lane * 4;

#define LDZ(c) ([&]() -> v4f {                                                  \
        const float* p_ = pZb - (c) * 256;                                      \
        if constexpr (ZAL) { return ldv(p_); }                                  \
        else { v4f z_; z_.x = p_[0]; z_.y = p_[1]; z_.z = p_[2]; z_.w = p_[3];  \
               return z_; } }())

    float sZm = 0.0f, sMt = 0.0f, sNum = 0.0f, sDen = 0.0f;

    // pipeline prologue: chunks 0 and 1 in flight
    v4f va = ldv(pV),       sa = ldv(pS),       za = LDZ(0);
    v4f vb = ldv(pV + 256), sb = ldv(pS + 256), zb = LDZ(1);

#pragma unroll 1
    for (int c = 0; c < 16; ++c) {
        const v4f vc_ = va, sc_ = sa, zc_ = za;
        va = vb; sa = sb; za = zb;
        if (c + 2 < 16) {                       // distance-2 prefetch
            vb = ldv(pV + (c + 2) * 256);
            sb = ldv(pS + (c + 2) * 256);
            zb = LDZ(c + 2);
        }
        const int a0 = c * 256 + lane * 4;
        const float vov[4]  = {vc_.x, vc_.y, vc_.z, vc_.w};
        const float lsv[4]  = {sc_.x, sc_.y, sc_.z, sc_.w};
        const float zrev[4] = {zc_.w, zc_.z, zc_.y, zc_.x};
        float vres[4];
#pragma unroll
        for (int k = 0; k < 4; ++k) {
            const int a = a0 + k;
            float V = vov[k] + DAc * (rp_m - vov[k]) * a_m + DAc * inT;
            if (a < 4) V = 0.0f;                // age < REF_T (a*DA < 0.004)
            float lam  = (V == 0.0f) ? 1e-8f : expf(V - ft_m);
            float p    = lam * DTc;
            float Plam = (p >= 0.01f) ? (1.0f - expf(-p)) : p;
            float S    = expf(lsv[k]);
            float mt   = S * zrev[k];
            sZm += mt * Plam;
            sMt += mt;
            float v = (1.0f - S) * mt;
            sNum += v * Plam;
            sDen += v;
            vres[k] = V;
        }
        v4f vo; vo.x = vres[0]; vo.y = vres[1]; vo.z = vres[2]; vo.w = vres[3];
        *reinterpret_cast<v4f*>(pO + c * 256) = vo;
    }
#undef LDZ

    // ---- NS loads issued now; latency hides under the wave reduction ----
    const float* pN = snv_in + rowS + lane * 4;
    const float* pL = snlf   + rowS + lane * 4;
    v4f n0 = ldv(pN), n1 = ldv(pN + 256), n2 = ldv(pN + 512), n3 = ldv(pN + 768);
    v4f l0 = ldv(pL), l1 = ldv(pL + 256), l2 = ldv(pL + 512), l3 = ldv(pL + 768);

    // ---- intra-wave reduction of the 4 sums (no LDS, no barrier) ----
    float vals[4] = {sZm, sMt, sNum, sDen};
#pragma unroll
    for (int i = 0; i < 4; ++i) {
        float v = vals[i];
        for (int off = 32; off > 0; off >>= 1) v += __shfl_down(v, off, 64);
        vals[i] = v;
    }
    if (lane == 0) {
        float Zm  = vals[0];
        float sM  = vals[1];
        float num = vals[2];
        float den = vals[3];
        float mess  = 1.0f - sM;
        float lam_t = (den != 0.0f) ? (num / den) : 0.0f;
        float Z = Zm + lam_t * mess;
        Z = fminf(fmaxf(Z, 0.0f), 1.0f);
        float At  = Z / DTc;
        float var = Z / 500.0f + 0.1f * DTc / 500.0f;
        float d   = ztn - Z;
        float znll = 0.5f * (d * d) / var + 0.5f * logf(var) + 0.5f * logf(2.0f * 3.14f);
        out[OFF_AT   + row] = At;
        out[OFF_Z    + row] = Z;
        out[OFF_ZNLL + row] = znll;
    }

    // ---- sampled-neuron compute (loads already in flight) ----
#define NSQ(nq, lq, q)                                                          \
    do {                                                                        \
        const float vv[4] = {nq.x, nq.y, nq.z, nq.w};                           \
        const float lf[4] = {lq.x, lq.y, lq.z, lq.w};                           \
        float vn[4], py[4], p1[4];                                              \
        _Pragma("unroll")                                                       \
        for (int k = 0; k < 4; ++k) {                                           \
            float V = vv[k] + DAc * (rp_m - vv[k]) * a_m + DAc * inT;           \
            if (lf[k] < 0.004f) V = 0.0f;           /* age < REF_T */           \
            float lam  = (V == 0.0f) ? 1e-8f : expf(V - ft_m);                  \
            float ltdt = lam * DTc;                                             \
            float Plam = (ltdt >= 0.01f) ? (1.0f - expf(-ltdt)) : ltdt;         \
            py[k] = (ltdt < 0.01f) ? (V - ft_m + LOG_DT) : logf(Plam);          \
            p1[k] = -ltdt;                                                      \
            vn[k] = V;                                                          \
        }                                                                       \
        const size_t s0 = rowS + (q) * 256 + lane * 4;                          \
        v4f o0; o0.x = vn[0]; o0.y = vn[1]; o0.z = vn[2]; o0.w = vn[3];         \
        v4f o1; o1.x = py[0]; o1.y = py[1]; o1.z = py[2]; o1.w = py[3];         \
        v4f o2; o2.x = p1[0]; o2.y = p1[1]; o2.z = p1[2]; o2.w = p1[3];         \
        *reinterpret_cast<v4f*>(out + OFF_SNV   + s0) = o0;                     \
        *reinterpret_cast<v4f*>(out + OFF_LNPY  + s0) = o1;                     \
        *reinterpret_cast<v4f*>(out + OFF_LNP1Y + s0) = o2;                     \
    } while (0)

    NSQ(n0, l0, 0);
    NSQ(n1, l1, 1);
    NSQ(n2, l2, 2);
    NSQ(n3, l3, 3);
#undef NSQ
}

__global__ __launch_bounds__(256, 4) void lif_kernel(
    const float* __restrict__ x,
    const float* __restrict__ V_t_old,
    const float* __restrict__ logS_t_old,
    const float* __restrict__ snv_in,
    const float* __restrict__ snlf,
    const float* __restrict__ I_syn,
    const float* __restrict__ amem,
    const float* __restrict__ asyn,
    const float* __restrict__ J,
    const float* __restrict__ rp,
    const float* __restrict__ ft,
    const float* __restrict__ eps,
    const float* __restrict__ Z_hist,
    const int*   __restrict__ clk_ptr,
    float* __restrict__ out)
{
    const int wid  = threadIdx.x >> 6;
    const int lane = threadIdx.x & 63;
    const int row  = blockIdx.x * 4 + wid;   // grid = 1024 blocks -> 4096 rows
    const int b    = row >> 4;
    const int m    = row & 15;

    // ---- uniform loads (wave-uniform: m, row are per-wave constants) ----
    const int    clk  = *clk_ptr;
    const float  xv   = x[row];
    const float  ev   = eps[0];
    const float  a_m  = amem[m];
    const float  rp_m = rp[m];
    const float  ft_m = ft[m];
    const size_t rowZ = (size_t)row * AT_;
    const float  ztn  = Z_hist[rowZ + clk + A_];

    // ---- per-wave prologue: I_syn update + inT (redundant per wave, no barrier) ----
    float asy = 0.0f, Iold = 0.0f, Jv = 0.0f, zl = 0.0f;
    if (lane < M_) {
        asy  = asyn[lane];
        Iold = I_syn[b * M_ + lane];
        Jv   = J[lane * M_ + m];
        if (clk > 1) zl = Z_hist[(size_t)(b * M_ + lane) * AT_ + (clk + A_ - 2)];
    }
    float In = Iold;
    if (clk > 1 && lane < M_) {              // SYN_DELAY_BINS = 1
        const float es = expf(-DTc * asy);
        In = es * Iold + (1.0f - es) * zl / DTc;
    }
    if (lane == m) out[OFF_ISYN + row] = In;   // this row's I_syn_new[b,m]
    float t = (lane < M_) ? In * Jv : 0.0f;
#pragma unroll
    for (int off = 8; off > 0; off >>= 1) t += __shfl_xor(t, off, 16);
    const float inT = __shfl(t, 0, 64) + xv * ev;

    if ((clk & 3) == 0) {
        do_row<true >(row, lane, clk, inT, a_m, rp_m, ft_m, ztn,
                      V_t_old, logS_t_old, snv_in, snlf, Z_hist, out);
    } else {
        do_row<false>(row, lane, clk, inT, a_m, rp_m, ft_m, ztn,
                      V_t_old, logS_t_old, snv_in, snlf, Z_hist, out);
    }
}

extern "C" void kernel_launch(void* const* d_in, const int* in_sizes, int n_in,
                              void* d_out, int out_size, void* d_ws, size_t ws_size,
                              hipStream_t stream) {
    lif_kernel<<<(B_ * M_) / 4, 256, 0, stream>>>(
        (const float*)d_in[0],   // x
        (const float*)d_in[1],   // V_t_old
        (const float*)d_in[2],   // logS_t_old
        (const float*)d_in[3],   // sampled_neuron_v
        (const float*)d_in[4],   // sampled_neuron_lastfire
        (const float*)d_in[5],   // I_syn
        (const float*)d_in[6],   // amem
        (const float*)d_in[7],   // asyn
        (const float*)d_in[8],   // J
        (const float*)d_in[9],   // rp
        (const float*)d_in[10],  // ft
        (const float*)d_in[11],  // eps
        (const float*)d_in[12],  // Z_hist_est
        (const int*)  d_in[13],  // internal_clock
        (float*)d_out);
}